// Round 13
// baseline (722.209 us; speedup 1.0000x reference)
//
#include <hip/hip_runtime.h>

#define NN 2048
#define NH 4
#define COLS 256   // NH*F_OUT

typedef __attribute__((ext_vector_type(8))) short short8;
typedef __attribute__((ext_vector_type(4))) float f32x4;
typedef __attribute__((ext_vector_type(4))) int i32x4;
typedef __attribute__((ext_vector_type(4))) unsigned u32x4;

__device__ __forceinline__ unsigned cvtpk(float lo, float hi) {
  unsigned r;
  asm("v_cvt_pk_bf16_f32 %0, %1, %2" : "=v"(r) : "v"(lo), "v"(hi));
  return r;
}
__device__ __forceinline__ unsigned pack16(i32x4 a, i32x4 b, i32x4 c, i32x4 d) {
  unsigned m = 0;
  #pragma unroll
  for (int e = 0; e < 4; ++e) {
    m |= (a[e] != 0 ? 1u : 0u) << e;
    m |= (b[e] != 0 ? 1u : 0u) << (e + 4);
    m |= (c[e] != 0 ? 1u : 0u) << (e + 8);
    m |= (d[e] != 0 ? 1u : 0u) << (e + 12);
  }
  return m;
}
__device__ __forceinline__ void gload_lds16(const void* g, void* l) {
  __builtin_amdgcn_global_load_lds(
      (const __attribute__((address_space(1))) void*)g,
      (__attribute__((address_space(3))) void*)l, 16, 0, 0);
}

#define ONES8 {(short)0x3F80, (short)0x3F80, (short)0x3F80, (short)0x3F80, \
               (short)0x3F80, (short)0x3F80, (short)0x3F80, (short)0x3F80}

// ---------------------------------------------------------------------------
// Kernel 1 (unchanged): h = X @ W; hB fragment-contiguous; s pre-scaled log2e.
// ---------------------------------------------------------------------------
__global__ __launch_bounds__(256) void k1_prep(
    const float* __restrict__ nf, const float* __restrict__ W,
    const float* __restrict__ att, ushort* __restrict__ hB,
    float* __restrict__ s_src, float* __restrict__ s_dst)
{
  const int tid = threadIdx.x;
  const int head = tid >> 6, lane = tid & 63;
  const int bid = blockIdx.x;
  const int m0 = bid * 8;

  float w[64];
  #pragma unroll
  for (int f = 0; f < 64; ++f) w[f] = W[f * COLS + tid];

  const float LOG2E = 1.4426950408889634f;
  const float asrc = att[head * 128 + lane] * LOG2E;
  const float adst = att[head * 128 + 64 + lane] * LOG2E;

  __shared__ float xs[512];
  xs[tid]       = nf[m0 * 64 + tid];
  xs[tid + 256] = nf[m0 * 64 + 256 + tid];
  __syncthreads();

  float hv[8];
  #pragma unroll
  for (int rr = 0; rr < 8; ++rr) {
    float acc = 0.f;
    #pragma unroll
    for (int f = 0; f < 64; ++f) acc = fmaf(xs[rr * 64 + f], w[f], acc);
    hv[rr] = acc;
    float vs = acc * asrc, vd = acc * adst;
    #pragma unroll
    for (int off = 32; off > 0; off >>= 1) {
      vs += __shfl_xor(vs, off);
      vd += __shfl_xor(vd, off);
    }
    if (lane == 0) {
      const int m = m0 + rr;
      const int b = m >> 11, n = m & (NN - 1);
      s_src[(b * NH + head) * NN + n] = vs;
      s_dst[(b * NH + head) * NN + n] = vd;
    }
  }

  const int b   = m0 >> 11;
  const int n0  = m0 & (NN - 1);
  const int jc  = n0 >> 5;
  const int grp = (n0 >> 3) & 3;
  const int t   = (tid >> 4) & 3, fl = tid & 15;
  uint4 vv;
  vv.x = cvtpk(hv[0], hv[1]);
  vv.y = cvtpk(hv[2], hv[3]);
  vv.z = cvtpk(hv[4], hv[5]);
  vv.w = cvtpk(hv[6], hv[7]);
  const size_t chunk =
      (((size_t)(b * NH + head) * 64 + jc) * 4 + t) * 64 + (grp * 16 + fl);
  *(uint4*)(hB + chunk * 8) = vv;
}

// ---------------------------------------------------------------------------
// Kernel 2 (unchanged r12 control): DMA double-buffer pipeline.
// ---------------------------------------------------------------------------
__global__ __launch_bounds__(256) void k2_main(
    const int* __restrict__ adj, const ushort* __restrict__ hB,
    const float* __restrict__ s_src, const float* __restrict__ s_dst,
    float* __restrict__ out)
{
  const int tid = threadIdx.x;
  const int h   = tid >> 6;
  const int l   = tid & 63;
  const int L   = blockIdx.x;
  const int xcd  = L & 7, pos = L >> 3;
  const int b    = xcd >> 1;
  const int iblk = (xcd & 1) * 64 + pos;
  const int i0   = iblk << 4;

  const int bh   = b * NH + h;
  const int r16  = l & 15;
  const int grp  = l >> 4;
  const int koff = grp << 3;

  __shared__ ushort  hbuf[NH][2][2048];
  __shared__ float   sdl[NH][NN];
  __shared__ unsigned abits[16][65];

  {
    const int srow = tid >> 4, sseg = tid & 15;
    const int* sb = adj + ((size_t)(b * NN + i0 + srow)) * NN + sseg * 128;
    #pragma unroll
    for (int p = 0; p < 4; ++p) {
      const i32x4 a0 = *(const i32x4*)(sb + p * 32);
      const i32x4 a1 = *(const i32x4*)(sb + p * 32 + 4);
      const i32x4 a2 = *(const i32x4*)(sb + p * 32 + 8);
      const i32x4 a3 = *(const i32x4*)(sb + p * 32 + 12);
      const i32x4 a4 = *(const i32x4*)(sb + p * 32 + 16);
      const i32x4 a5 = *(const i32x4*)(sb + p * 32 + 20);
      const i32x4 a6 = *(const i32x4*)(sb + p * 32 + 24);
      const i32x4 a7 = *(const i32x4*)(sb + p * 32 + 28);
      abits[srow][sseg * 4 + p] = pack16(a0, a1, a2, a3) | (pack16(a4, a5, a6, a7) << 16);
    }
  }
  {
    const int sh = tid >> 6, sc = tid & 63;
    const float* sp = s_dst + (size_t)(b * NH + sh) * NN + sc * 32;
    float* dp = &sdl[sh][sc * 32];
    #pragma unroll
    for (int k = 0; k < 8; ++k)
      *(f32x4*)(dp + k * 4) = *(const f32x4*)(sp + k * 4);
  }
  __syncthreads();

  const float ssl = s_src[bh * NN + i0 + r16];
  const ushort* hbSrc = hB + (size_t)bh * 131072 + l * 8;
  const short8 ones = ONES8;

  f32x4 acc[4];
  #pragma unroll
  for (int q = 0; q < 4; ++q) acc[q] = (f32x4){0.f, 0.f, 0.f, 0.f};
  f32x4 acd = (f32x4){0.f, 0.f, 0.f, 0.f};

#define STAGE(JC, BUF)                                                   \
  {                                                                      \
    _Pragma("unroll")                                                    \
    for (int t = 0; t < 4; ++t)                                          \
      gload_lds16(hbSrc + (JC) * 2048 + t * 512, &hbuf[h][(BUF)][t * 512]); \
  }
  STAGE(0, 0);
  STAGE(1, 1);

  #pragma unroll 1
  for (int jc = 0; jc < 64; ++jc) {
    const int buf = jc & 1;
    asm volatile("s_waitcnt vmcnt(4)" ::: "memory");
    const short8 hb0 = *(const short8*)&hbuf[h][buf][l * 8];
    const short8 hb1 = *(const short8*)&hbuf[h][buf][512 + l * 8];
    const short8 hb2 = *(const short8*)&hbuf[h][buf][1024 + l * 8];
    const short8 hb3 = *(const short8*)&hbuf[h][buf][1536 + l * 8];
    const int jb = jc * 32 + koff;
    const f32x4 sd0 = *(const f32x4*)&sdl[h][jb];
    const f32x4 sd1 = *(const f32x4*)&sdl[h][jb + 4];
    const unsigned msk = abits[r16][jc] >> koff;
    asm volatile("s_waitcnt lgkmcnt(0)" ::: "memory");
    __builtin_amdgcn_sched_barrier(0);
    if (jc < 62) STAGE(jc + 2, buf);

    float pl[8];
    #pragma unroll
    for (int e = 0; e < 8; ++e) {
      const float sdv = (e < 4) ? sd0[e] : sd1[e - 4];
      float x = ssl + sdv;
      x = fmaxf(x, 0.2f * x);
      const float p = __builtin_amdgcn_exp2f(x);
      pl[e] = ((msk >> e) & 1u) ? p : 0.f;
    }
    u32x4 pa;
    #pragma unroll
    for (int e2 = 0; e2 < 4; ++e2) pa[e2] = cvtpk(pl[2 * e2], pl[2 * e2 + 1]);
    union { u32x4 u; short8 s; } ca; ca.u = pa;
    const short8 pal = ca.s;

    acc[0] = __builtin_amdgcn_mfma_f32_16x16x32_bf16(pal, hb0, acc[0], 0, 0, 0);
    acc[1] = __builtin_amdgcn_mfma_f32_16x16x32_bf16(pal, hb1, acc[1], 0, 0, 0);
    acc[2] = __builtin_amdgcn_mfma_f32_16x16x32_bf16(pal, hb2, acc[2], 0, 0, 0);
    acc[3] = __builtin_amdgcn_mfma_f32_16x16x32_bf16(pal, hb3, acc[3], 0, 0, 0);
    acd    = __builtin_amdgcn_mfma_f32_16x16x32_bf16(pal, ones,    acd,    0, 0, 0);
  }
#undef STAGE

  float rl[4];
  #pragma unroll
  for (int r = 0; r < 4; ++r) rl[r] = 1.0f / acd[r];
  #pragma unroll
  for (int t = 0; t < 4; ++t) {
    #pragma unroll
    for (int r = 0; r < 4; ++r) {
      const int i = i0 + grp * 4 + r;
      const size_t oidx = ((size_t)(b * NN + i) * COLS) + h * 64 + t * 16 + r16;
      out[oidx] = acc[t][r] * rl[r];
    }
  }
}

// ---------------------------------------------------------------------------
// ABLATION a1_noHB (rep x16): P-gen only. sdl+abits staging, exp chain,
// cvtpk, 5 MFMA with B=ones. NO hB delivery. asm keep-alives prevent DCE.
// ---------------------------------------------------------------------------
__global__ __launch_bounds__(256) void a1_noHB(
    const int* __restrict__ adj, const float* __restrict__ s_src,
    const float* __restrict__ s_dst)
{
  const int tid = threadIdx.x;
  const int h   = tid >> 6;
  const int l   = tid & 63;
  const int L   = blockIdx.x;
  const int xcd  = L & 7, pos = L >> 3;
  const int b    = xcd >> 1;
  const int iblk = (xcd & 1) * 64 + pos;
  const int i0   = iblk << 4;
  const int bh   = b * NH + h;
  const int r16  = l & 15;
  const int grp  = l >> 4;
  const int koff = grp << 3;

  __shared__ float   sdl[NH][NN];
  __shared__ unsigned abits[16][65];

  {
    const int srow = tid >> 4, sseg = tid & 15;
    const int* sb = adj + ((size_t)(b * NN + i0 + srow)) * NN + sseg * 128;
    #pragma unroll
    for (int p = 0; p < 4; ++p) {
      const i32x4 a0 = *(const i32x4*)(sb + p * 32);
      const i32x4 a1 = *(const i32x4*)(sb + p * 32 + 4);
      const i32x4 a2 = *(const i32x4*)(sb + p * 32 + 8);
      const i32x4 a3 = *(const i32x4*)(sb + p * 32 + 12);
      const i32x4 a4 = *(const i32x4*)(sb + p * 32 + 16);
      const i32x4 a5 = *(const i32x4*)(sb + p * 32 + 20);
      const i32x4 a6 = *(const i32x4*)(sb + p * 32 + 24);
      const i32x4 a7 = *(const i32x4*)(sb + p * 32 + 28);
      abits[srow][sseg * 4 + p] = pack16(a0, a1, a2, a3) | (pack16(a4, a5, a6, a7) << 16);
    }
  }
  {
    const int sh = tid >> 6, sc = tid & 63;
    const float* sp = s_dst + (size_t)(b * NH + sh) * NN + sc * 32;
    float* dp = &sdl[sh][sc * 32];
    #pragma unroll
    for (int k = 0; k < 8; ++k)
      *(f32x4*)(dp + k * 4) = *(const f32x4*)(sp + k * 4);
  }
  __syncthreads();

  const float ssl = s_src[bh * NN + i0 + r16];
  const short8 ones = ONES8;
  f32x4 acc[4];
  #pragma unroll
  for (int q = 0; q < 4; ++q) acc[q] = (f32x4){0.f, 0.f, 0.f, 0.f};
  f32x4 acd = (f32x4){0.f, 0.f, 0.f, 0.f};

  #pragma unroll 1
  for (int rep = 0; rep < 16; ++rep) {
    const float sslr = ssl + (float)rep * 1e-30f;
    #pragma unroll 1
    for (int jc = 0; jc < 64; ++jc) {
      const int jb = jc * 32 + koff;
      const f32x4 sd0 = *(const f32x4*)&sdl[h][jb];
      const f32x4 sd1 = *(const f32x4*)&sdl[h][jb + 4];
      const unsigned msk = abits[r16][jc] >> koff;
      float pl[8];
      #pragma unroll
      for (int e = 0; e < 8; ++e) {
        const float sdv = (e < 4) ? sd0[e] : sd1[e - 4];
        float x = sslr + sdv;
        x = fmaxf(x, 0.2f * x);
        const float p = __builtin_amdgcn_exp2f(x);
        pl[e] = ((msk >> e) & 1u) ? p : 0.f;
      }
      u32x4 pa;
      #pragma unroll
      for (int e2 = 0; e2 < 4; ++e2) pa[e2] = cvtpk(pl[2 * e2], pl[2 * e2 + 1]);
      union { u32x4 u; short8 s; } ca; ca.u = pa;
      const short8 pal = ca.s;
      acc[0] = __builtin_amdgcn_mfma_f32_16x16x32_bf16(pal, ones, acc[0], 0, 0, 0);
      acc[1] = __builtin_amdgcn_mfma_f32_16x16x32_bf16(pal, ones, acc[1], 0, 0, 0);
      acc[2] = __builtin_amdgcn_mfma_f32_16x16x32_bf16(pal, ones, acc[2], 0, 0, 0);
      acc[3] = __builtin_amdgcn_mfma_f32_16x16x32_bf16(pal, ones, acc[3], 0, 0, 0);
      acd    = __builtin_amdgcn_mfma_f32_16x16x32_bf16(pal, ones, acd,    0, 0, 0);
    }
  }
  asm volatile("" :: "v"(acc[0][0]), "v"(acc[1][0]), "v"(acc[2][0]),
                     "v"(acc[3][0]), "v"(acd[0]));
}

// ---------------------------------------------------------------------------
// ABLATION a2_noP (rep x4): hB delivery only. DMA double-buffer + vmcnt/lgkm
// waits + ds_reads + 5 MFMA with A=ones. NO softmax VALU.
// ---------------------------------------------------------------------------
__global__ __launch_bounds__(256) void a2_noP(const ushort* __restrict__ hB)
{
  const int tid = threadIdx.x;
  const int h   = tid >> 6;
  const int l   = tid & 63;
  const int L   = blockIdx.x;
  const int xcd  = L & 7;
  const int b    = xcd >> 1;
  const int bh   = b * NH + h;

  __shared__ ushort hbuf[NH][2][2048];
  const ushort* hbSrc = hB + (size_t)bh * 131072 + l * 8;
  const short8 ones = ONES8;

  f32x4 acc[4];
  #pragma unroll
  for (int q = 0; q < 4; ++q) acc[q] = (f32x4){0.f, 0.f, 0.f, 0.f};
  f32x4 acd = (f32x4){0.f, 0.f, 0.f, 0.f};

#define STAGE2(JC, BUF)                                                  \
  {                                                                      \
    _Pragma("unroll")                                                    \
    for (int t = 0; t < 4; ++t)                                          \
      gload_lds16(hbSrc + (JC) * 2048 + t * 512, &hbuf[h][(BUF)][t * 512]); \
  }
  #pragma unroll 1
  for (int rep = 0; rep < 4; ++rep) {
    STAGE2(0, 0);
    STAGE2(1, 1);
    #pragma unroll 1
    for (int jc = 0; jc < 64; ++jc) {
      const int buf = jc & 1;
      asm volatile("s_waitcnt vmcnt(4)" ::: "memory");
      const short8 hb0 = *(const short8*)&hbuf[h][buf][l * 8];
      const short8 hb1 = *(const short8*)&hbuf[h][buf][512 + l * 8];
      const short8 hb2 = *(const short8*)&hbuf[h][buf][1024 + l * 8];
      const short8 hb3 = *(const short8*)&hbuf[h][buf][1536 + l * 8];
      asm volatile("s_waitcnt lgkmcnt(0)" ::: "memory");
      __builtin_amdgcn_sched_barrier(0);
      if (jc < 62) STAGE2(jc + 2, buf);
      acc[0] = __builtin_amdgcn_mfma_f32_16x16x32_bf16(ones, hb0, acc[0], 0, 0, 0);
      acc[1] = __builtin_amdgcn_mfma_f32_16x16x32_bf16(ones, hb1, acc[1], 0, 0, 0);
      acc[2] = __builtin_amdgcn_mfma_f32_16x16x32_bf16(ones, hb2, acc[2], 0, 0, 0);
      acc[3] = __builtin_amdgcn_mfma_f32_16x16x32_bf16(ones, hb3, acc[3], 0, 0, 0);
      acd    = __builtin_amdgcn_mfma_f32_16x16x32_bf16(ones, hb0, acd,    0, 0, 0);
    }
  }
#undef STAGE2
  asm volatile("" :: "v"(acc[0][0]), "v"(acc[1][0]), "v"(acc[2][0]),
                     "v"(acc[3][0]), "v"(acd[0]));
}

// ---------------------------------------------------------------------------
// ABLATION a3_reg (rep x8): FULL compute, hB via register global loads with
// 2-deep rotation; every load pinned at issue via asm "+v" (no sinking).
// ---------------------------------------------------------------------------
__global__ __launch_bounds__(256) void a3_reg(
    const int* __restrict__ adj, const ushort* __restrict__ hB,
    const float* __restrict__ s_src, const float* __restrict__ s_dst)
{
  const int tid = threadIdx.x;
  const int h   = tid >> 6;
  const int l   = tid & 63;
  const int L   = blockIdx.x;
  const int xcd  = L & 7, pos = L >> 3;
  const int b    = xcd >> 1;
  const int iblk = (xcd & 1) * 64 + pos;
  const int i0   = iblk << 4;
  const int bh   = b * NH + h;
  const int r16  = l & 15;
  const int grp  = l >> 4;
  const int koff = grp << 3;

  __shared__ float   sdl[NH][NN];
  __shared__ unsigned abits[16][65];

  {
    const int srow = tid >> 4, sseg = tid & 15;
    const int* sb = adj + ((size_t)(b * NN + i0 + srow)) * NN + sseg * 128;
    #pragma unroll
    for (int p = 0; p < 4; ++p) {
      const i32x4 a0 = *(const i32x4*)(sb + p * 32);
      const i32x4 a1 = *(const i32x4*)(sb + p * 32 + 4);
      const i32x4 a2 = *(const i32x4*)(sb + p * 32 + 8);
      const i32x4 a3 = *(const i32x4*)(sb + p * 32 + 12);
      const i32x4 a4 = *(const i32x4*)(sb + p * 32 + 16);
      const i32x4 a5 = *(const i32x4*)(sb + p * 32 + 20);
      const i32x4 a6 = *(const i32x4*)(sb + p * 32 + 24);
      const i32x4 a7 = *(const i32x4*)(sb + p * 32 + 28);
      abits[srow][sseg * 4 + p] = pack16(a0, a1, a2, a3) | (pack16(a4, a5, a6, a7) << 16);
    }
  }
  {
    const int sh = tid >> 6, sc = tid & 63;
    const float* sp = s_dst + (size_t)(b * NH + sh) * NN + sc * 32;
    float* dp = &sdl[sh][sc * 32];
    #pragma unroll
    for (int k = 0; k < 8; ++k)
      *(f32x4*)(dp + k * 4) = *(const f32x4*)(sp + k * 4);
  }
  __syncthreads();

  const float ssl = s_src[bh * NN + i0 + r16];
  const ushort* hbSrc = hB + (size_t)bh * 131072 + l * 8;
  const short8 ones = ONES8;
  f32x4 acc[4];
  #pragma unroll
  for (int q = 0; q < 4; ++q) acc[q] = (f32x4){0.f, 0.f, 0.f, 0.f};
  f32x4 acd = (f32x4){0.f, 0.f, 0.f, 0.f};

#define LOADQ(D0, D1, D2, D3, JC)                          \
  D0 = *(const short8*)(hbSrc + (JC) * 2048);              \
  D1 = *(const short8*)(hbSrc + (JC) * 2048 + 512);        \
  D2 = *(const short8*)(hbSrc + (JC) * 2048 + 1024);       \
  D3 = *(const short8*)(hbSrc + (JC) * 2048 + 1536);       \
  asm volatile("" : "+v"(D0), "+v"(D1), "+v"(D2), "+v"(D3));

  #pragma unroll 1
  for (int rep = 0; rep < 8; ++rep) {
    const float sslr = ssl + (float)rep * 1e-30f;
    short8 c0, c1, c2, c3, n0, n1, n2, n3;
    LOADQ(c0, c1, c2, c3, 0);
    LOADQ(n0, n1, n2, n3, 1);
    #pragma unroll 1
    for (int jc = 0; jc < 64; ++jc) {
      const int jp = (jc + 2 < 64) ? jc + 2 : 63;
      short8 m0, m1, m2, m3;
      LOADQ(m0, m1, m2, m3, jp);

      const int jb = jc * 32 + koff;
      const f32x4 sd0 = *(const f32x4*)&sdl[h][jb];
      const f32x4 sd1 = *(const f32x4*)&sdl[h][jb + 4];
      const unsigned msk = abits[r16][jc] >> koff;
      float pl[8];
      #pragma unroll
      for (int e = 0; e < 8; ++e) {
        const float sdv = (e < 4) ? sd0[e] : sd1[e - 4];
        float x = sslr + sdv;
        x = fmaxf(x, 0.2f * x);
        const float p = __builtin_amdgcn_exp2f(x);
        pl[e] = ((msk >> e) & 1u) ? p : 0.f;
      }
      u32x4 pa;
      #pragma unroll
      for (int e2 = 0; e2 < 4; ++e2) pa[e2] = cvtpk(pl[2 * e2], pl[2 * e2 + 1]);
      union { u32x4 u; short8 s; } ca; ca.u = pa;
      const short8 pal = ca.s;

      acc[0] = __builtin_amdgcn_mfma_f32_16x16x32_bf16(pal, c0, acc[0], 0, 0, 0);
      acc[1] = __builtin_amdgcn_mfma_f32_16x16x32_bf16(pal, c1, acc[1], 0, 0, 0);
      acc[2] = __builtin_amdgcn_mfma_f32_16x16x32_bf16(pal, c2, acc[2], 0, 0, 0);
      acc[3] = __builtin_amdgcn_mfma_f32_16x16x32_bf16(pal, c3, acc[3], 0, 0, 0);
      acd    = __builtin_amdgcn_mfma_f32_16x16x32_bf16(pal, ones, acd,   0, 0, 0);

      c0 = n0; c1 = n1; c2 = n2; c3 = n3;
      n0 = m0; n1 = m1; n2 = m2; n3 = m3;
    }
  }
#undef LOADQ
  asm volatile("" :: "v"(acc[0][0]), "v"(acc[1][0]), "v"(acc[2][0]),
                     "v"(acc[3][0]), "v"(acd[0]));
}

// ---------------------------------------------------------------------------
extern "C" void kernel_launch(void* const* d_in, const int* in_sizes, int n_in,
                              void* d_out, int out_size, void* d_ws, size_t ws_size,
                              hipStream_t stream) {
  const float* nf  = (const float*)d_in[0];
  const int*   adj = (const int*)d_in[1];
  const float* W   = (const float*)d_in[2];
  const float* att = (const float*)d_in[3];

  ushort* hB    = (ushort*)d_ws;                                  // 4 MB
  float*  s_src = (float*)((char*)d_ws + (size_t)16 * 64 * NN * 2);
  float*  s_dst = s_src + 16 * NN;

  hipLaunchKernelGGL(k1_prep, dim3(1024), dim3(256), 0, stream,
                     nf, W, att, hB, s_src, s_dst);
  hipLaunchKernelGGL(k2_main, dim3(512), dim3(256), 0, stream,
                     adj, hB, s_src, s_dst, (float*)d_out);
  // ---- diagnostic ablations (write nothing; keep-alive via asm) ----
  hipLaunchKernelGGL(a1_noHB, dim3(512), dim3(256), 0, stream,
                     adj, s_src, s_dst);
  hipLaunchKernelGGL(a2_noP, dim3(512), dim3(256), 0, stream, hB);
  hipLaunchKernelGGL(a3_reg, dim3(512), dim3(256), 0, stream,
                     adj, hB, s_src, s_dst);
}

// Round 14
// 64.029 us; speedup vs baseline: 11.2795x; 11.2795x over previous
//
#include <hip/hip_runtime.h>

#define NN 2048
#define NH 4
#define COLS 256   // NH*F_OUT

typedef __attribute__((ext_vector_type(8))) short short8;
typedef __attribute__((ext_vector_type(4))) float f32x4;
typedef __attribute__((ext_vector_type(4))) int i32x4;
typedef __attribute__((ext_vector_type(4))) unsigned u32x4;

__device__ __forceinline__ unsigned cvtpk(float lo, float hi) {
  unsigned r;
  asm("v_cvt_pk_bf16_f32 %0, %1, %2" : "=v"(r) : "v"(lo), "v"(hi));
  return r;
}
__device__ __forceinline__ unsigned pack16(i32x4 a, i32x4 b, i32x4 c, i32x4 d) {
  unsigned m = 0;
  #pragma unroll
  for (int e = 0; e < 4; ++e) {
    m |= (a[e] != 0 ? 1u : 0u) << e;
    m |= (b[e] != 0 ? 1u : 0u) << (e + 4);
    m |= (c[e] != 0 ? 1u : 0u) << (e + 8);
    m |= (d[e] != 0 ? 1u : 0u) << (e + 12);
  }
  return m;
}

#define ONES8 {(short)0x3F80, (short)0x3F80, (short)0x3F80, (short)0x3F80, \
               (short)0x3F80, (short)0x3F80, (short)0x3F80, (short)0x3F80}

// ---------------------------------------------------------------------------
// Kernel 1 (unchanged): h = X @ W; hB fragment-contiguous; s pre-scaled log2e.
// ---------------------------------------------------------------------------
__global__ __launch_bounds__(256) void k1_prep(
    const float* __restrict__ nf, const float* __restrict__ W,
    const float* __restrict__ att, ushort* __restrict__ hB,
    float* __restrict__ s_src, float* __restrict__ s_dst)
{
  const int tid = threadIdx.x;
  const int head = tid >> 6, lane = tid & 63;
  const int bid = blockIdx.x;
  const int m0 = bid * 8;

  float w[64];
  #pragma unroll
  for (int f = 0; f < 64; ++f) w[f] = W[f * COLS + tid];

  const float LOG2E = 1.4426950408889634f;
  const float asrc = att[head * 128 + lane] * LOG2E;
  const float adst = att[head * 128 + 64 + lane] * LOG2E;

  __shared__ float xs[512];
  xs[tid]       = nf[m0 * 64 + tid];
  xs[tid + 256] = nf[m0 * 64 + 256 + tid];
  __syncthreads();

  float hv[8];
  #pragma unroll
  for (int rr = 0; rr < 8; ++rr) {
    float acc = 0.f;
    #pragma unroll
    for (int f = 0; f < 64; ++f) acc = fmaf(xs[rr * 64 + f], w[f], acc);
    hv[rr] = acc;
    float vs = acc * asrc, vd = acc * adst;
    #pragma unroll
    for (int off = 32; off > 0; off >>= 1) {
      vs += __shfl_xor(vs, off);
      vd += __shfl_xor(vd, off);
    }
    if (lane == 0) {
      const int m = m0 + rr;
      const int b = m >> 11, n = m & (NN - 1);
      s_src[(b * NH + head) * NN + n] = vs;
      s_dst[(b * NH + head) * NN + n] = vd;
    }
  }

  const int b   = m0 >> 11;
  const int n0  = m0 & (NN - 1);
  const int jc  = n0 >> 5;
  const int grp = (n0 >> 3) & 3;
  const int t   = (tid >> 4) & 3, fl = tid & 15;
  uint4 vv;
  vv.x = cvtpk(hv[0], hv[1]);
  vv.y = cvtpk(hv[2], hv[3]);
  vv.z = cvtpk(hv[4], hv[5]);
  vv.w = cvtpk(hv[6], hv[7]);
  const size_t chunk =
      (((size_t)(b * NH + head) * 64 + jc) * 4 + t) * 64 + (grp * 16 + fl);
  *(uint4*)(hB + chunk * 8) = vv;
}

// ---------------------------------------------------------------------------
// Kernel 2 = promoted a3_reg: register-pinned 2-deep hB prefetch (the r13
// ablation showed this fully hides hB delivery under the P-gen VALU, which
// is the measured wall: a1_noHB = 24.6us/rep @ VALUBusy 90%).
// grid 512 x 256 (4 waves = heads), 16 i-rows/block. LDS 37KB caps the
// backend occupancy target at 4 waves/EU -> 128-VGPR budget -> prefetch
// lives in registers (r9/r10/r11 starvation root-caused and avoided).
// sdl staged with instruction-contiguous b128 writes (conflict-free; the
// 933k conflicts in r12/r13 were the old strided staging).
// ---------------------------------------------------------------------------
__global__ __launch_bounds__(256) void k2_main(
    const int* __restrict__ adj, const ushort* __restrict__ hB,
    const float* __restrict__ s_src, const float* __restrict__ s_dst,
    float* __restrict__ out)
{
  const int tid = threadIdx.x;
  const int h   = tid >> 6;
  const int l   = tid & 63;
  const int L   = blockIdx.x;
  const int xcd  = L & 7, pos = L >> 3;
  const int b    = xcd >> 1;
  const int iblk = (xcd & 1) * 64 + pos;
  const int i0   = iblk << 4;
  const int bh   = b * NH + h;
  const int r16  = l & 15;
  const int grp  = l >> 4;
  const int koff = grp << 3;

  __shared__ float    sdl[NH * NN];      // 32KB, flat [h*2048 + n]
  __shared__ unsigned abits[16][65];     // 4.2KB

  // ---- stage adj -> bits
  {
    const int srow = tid >> 4, sseg = tid & 15;
    const int* sb = adj + ((size_t)(b * NN + i0 + srow)) * NN + sseg * 128;
    #pragma unroll
    for (int p = 0; p < 4; ++p) {
      const i32x4 a0 = *(const i32x4*)(sb + p * 32);
      const i32x4 a1 = *(const i32x4*)(sb + p * 32 + 4);
      const i32x4 a2 = *(const i32x4*)(sb + p * 32 + 8);
      const i32x4 a3 = *(const i32x4*)(sb + p * 32 + 12);
      const i32x4 a4 = *(const i32x4*)(sb + p * 32 + 16);
      const i32x4 a5 = *(const i32x4*)(sb + p * 32 + 20);
      const i32x4 a6 = *(const i32x4*)(sb + p * 32 + 24);
      const i32x4 a7 = *(const i32x4*)(sb + p * 32 + 28);
      abits[srow][sseg * 4 + p] = pack16(a0, a1, a2, a3) | (pack16(a4, a5, a6, a7) << 16);
    }
  }
  // ---- stage s_dst (all heads), instruction-contiguous: conflict-free
  {
    const float* sp = s_dst + (size_t)b * NH * NN;   // 8192 floats
    #pragma unroll
    for (int k = 0; k < 8; ++k) {
      const int di = k * 1024 + tid * 4;
      *(f32x4*)&sdl[di] = *(const f32x4*)(sp + di);
    }
  }
  __syncthreads();

  const float ssl = s_src[bh * NN + i0 + r16];
  const ushort* hbSrc = hB + (size_t)bh * 131072 + l * 8;
  const short8 ones = ONES8;
  const float* sdh = &sdl[h * NN];

  f32x4 acc[4];
  #pragma unroll
  for (int q = 0; q < 4; ++q) acc[q] = (f32x4){0.f, 0.f, 0.f, 0.f};
  f32x4 acd = (f32x4){0.f, 0.f, 0.f, 0.f};

#define LOADQ(D0, D1, D2, D3, JC)                          \
  D0 = *(const short8*)(hbSrc + (JC) * 2048);              \
  D1 = *(const short8*)(hbSrc + (JC) * 2048 + 512);        \
  D2 = *(const short8*)(hbSrc + (JC) * 2048 + 1024);       \
  D3 = *(const short8*)(hbSrc + (JC) * 2048 + 1536);       \
  asm volatile("" : "+v"(D0), "+v"(D1), "+v"(D2), "+v"(D3));

  short8 c0, c1, c2, c3, n0, n1, n2, n3;
  LOADQ(c0, c1, c2, c3, 0);
  LOADQ(n0, n1, n2, n3, 1);

  #pragma unroll 1
  for (int jc = 0; jc < 64; ++jc) {
    const int jp = (jc + 2 < 64) ? jc + 2 : 63;
    short8 m0, m1, m2, m3;
    LOADQ(m0, m1, m2, m3, jp);

    const int jb = jc * 32 + koff;
    const f32x4 sd0 = *(const f32x4*)(sdh + jb);
    const f32x4 sd1 = *(const f32x4*)(sdh + jb + 4);
    const unsigned msk = abits[r16][jc] >> koff;

    float pl[8];
    #pragma unroll
    for (int e = 0; e < 8; ++e) {
      const float sdv = (e < 4) ? sd0[e] : sd1[e - 4];
      float x = ssl + sdv;                 // pre-scaled by log2(e)
      x = fmaxf(x, 0.2f * x);
      const float p = __builtin_amdgcn_exp2f(x);
      pl[e] = ((msk >> e) & 1u) ? p : 0.f;
    }
    u32x4 pa;
    #pragma unroll
    for (int e2 = 0; e2 < 4; ++e2) pa[e2] = cvtpk(pl[2 * e2], pl[2 * e2 + 1]);
    union { u32x4 u; short8 s; } ca; ca.u = pa;
    const short8 pal = ca.s;

    acc[0] = __builtin_amdgcn_mfma_f32_16x16x32_bf16(pal, c0, acc[0], 0, 0, 0);
    acc[1] = __builtin_amdgcn_mfma_f32_16x16x32_bf16(pal, c1, acc[1], 0, 0, 0);
    acc[2] = __builtin_amdgcn_mfma_f32_16x16x32_bf16(pal, c2, acc[2], 0, 0, 0);
    acc[3] = __builtin_amdgcn_mfma_f32_16x16x32_bf16(pal, c3, acc[3], 0, 0, 0);
    acd    = __builtin_amdgcn_mfma_f32_16x16x32_bf16(pal, ones, acd,   0, 0, 0);

    c0 = n0; c1 = n1; c2 = n2; c3 = n3;
    n0 = m0; n1 = m1; n2 = m2; n3 = m3;
  }
#undef LOADQ

  float rl[4];
  #pragma unroll
  for (int r = 0; r < 4; ++r) rl[r] = 1.0f / acd[r];
  #pragma unroll
  for (int t = 0; t < 4; ++t) {
    #pragma unroll
    for (int r = 0; r < 4; ++r) {
      const int i = i0 + grp * 4 + r;
      const size_t oidx = ((size_t)(b * NN + i) * COLS) + h * 64 + t * 16 + r16;
      out[oidx] = acc[t][r] * rl[r];
    }
  }
}

// ---------------------------------------------------------------------------
extern "C" void kernel_launch(void* const* d_in, const int* in_sizes, int n_in,
                              void* d_out, int out_size, void* d_ws, size_t ws_size,
                              hipStream_t stream) {
  const float* nf  = (const float*)d_in[0];
  const int*   adj = (const int*)d_in[1];
  const float* W   = (const float*)d_in[2];
  const float* att = (const float*)d_in[3];

  ushort* hB    = (ushort*)d_ws;                                  // 4 MB
  float*  s_src = (float*)((char*)d_ws + (size_t)16 * 64 * NN * 2);
  float*  s_dst = s_src + 16 * NN;

  hipLaunchKernelGGL(k1_prep, dim3(1024), dim3(256), 0, stream,
                     nf, W, att, hB, s_src, s_dst);
  hipLaunchKernelGGL(k2_main, dim3(512), dim3(256), 0, stream,
                     adj, hB, s_src, s_dst, (float*)d_out);
}

// Round 15
// 56.333 us; speedup vs baseline: 12.8204x; 1.1366x over previous
//
#include <hip/hip_runtime.h>

#define NN 2048
#define NH 4
#define COLS 256   // NH*F_OUT

typedef __attribute__((ext_vector_type(8))) short short8;
typedef __attribute__((ext_vector_type(4))) float f32x4;
typedef __attribute__((ext_vector_type(4))) int i32x4;
typedef __attribute__((ext_vector_type(4))) unsigned u32x4;

__device__ __forceinline__ unsigned cvtpk(float lo, float hi) {
  unsigned r;
  asm("v_cvt_pk_bf16_f32 %0, %1, %2" : "=v"(r) : "v"(lo), "v"(hi));
  return r;
}
__device__ __forceinline__ unsigned pack16(i32x4 a, i32x4 b, i32x4 c, i32x4 d) {
  unsigned m = 0;
  #pragma unroll
  for (int e = 0; e < 4; ++e) {
    m |= (a[e] != 0 ? 1u : 0u) << e;
    m |= (b[e] != 0 ? 1u : 0u) << (e + 4);
    m |= (c[e] != 0 ? 1u : 0u) << (e + 8);
    m |= (d[e] != 0 ? 1u : 0u) << (e + 12);
  }
  return m;
}
__device__ __forceinline__ void gload_lds16(const void* g, void* l) {
  __builtin_amdgcn_global_load_lds(
      (const __attribute__((address_space(1))) void*)g,
      (__attribute__((address_space(3))) void*)l, 16, 0, 0);
}

#define ONES8 {(short)0x3F80, (short)0x3F80, (short)0x3F80, (short)0x3F80, \
               (short)0x3F80, (short)0x3F80, (short)0x3F80, (short)0x3F80}

// ---------------------------------------------------------------------------
// Kernel 1 (unchanged): h = X @ W; hB fragment-contiguous; s pre-scaled log2e.
// ---------------------------------------------------------------------------
__global__ __launch_bounds__(256) void k1_prep(
    const float* __restrict__ nf, const float* __restrict__ W,
    const float* __restrict__ att, ushort* __restrict__ hB,
    float* __restrict__ s_src, float* __restrict__ s_dst)
{
  const int tid = threadIdx.x;
  const int head = tid >> 6, lane = tid & 63;
  const int bid = blockIdx.x;
  const int m0 = bid * 8;

  float w[64];
  #pragma unroll
  for (int f = 0; f < 64; ++f) w[f] = W[f * COLS + tid];

  const float LOG2E = 1.4426950408889634f;
  const float asrc = att[head * 128 + lane] * LOG2E;
  const float adst = att[head * 128 + 64 + lane] * LOG2E;

  __shared__ float xs[512];
  xs[tid]       = nf[m0 * 64 + tid];
  xs[tid + 256] = nf[m0 * 64 + 256 + tid];
  __syncthreads();

  float hv[8];
  #pragma unroll
  for (int rr = 0; rr < 8; ++rr) {
    float acc = 0.f;
    #pragma unroll
    for (int f = 0; f < 64; ++f) acc = fmaf(xs[rr * 64 + f], w[f], acc);
    hv[rr] = acc;
    float vs = acc * asrc, vd = acc * adst;
    #pragma unroll
    for (int off = 32; off > 0; off >>= 1) {
      vs += __shfl_xor(vs, off);
      vd += __shfl_xor(vd, off);
    }
    if (lane == 0) {
      const int m = m0 + rr;
      const int b = m >> 11, n = m & (NN - 1);
      s_src[(b * NH + head) * NN + n] = vs;
      s_dst[(b * NH + head) * NN + n] = vd;
    }
  }

  const int b   = m0 >> 11;
  const int n0  = m0 & (NN - 1);
  const int jc  = n0 >> 5;
  const int grp = (n0 >> 3) & 3;
  const int t   = (tid >> 4) & 3, fl = tid & 15;
  uint4 vv;
  vv.x = cvtpk(hv[0], hv[1]);
  vv.y = cvtpk(hv[2], hv[3]);
  vv.z = cvtpk(hv[4], hv[5]);
  vv.w = cvtpk(hv[6], hv[7]);
  const size_t chunk =
      (((size_t)(b * NH + head) * 64 + jc) * 4 + t) * 64 + (grp * 16 + fl);
  *(uint4*)(hB + chunk * 8) = vv;
}

// ---------------------------------------------------------------------------
// Kernel 2: 256 blocks x 512 thr (8 waves = 4 heads x 2 j-halves),
// 32 i-rows/block (2 i-subtiles per wave -> hB L2 traffic halved).
// hB via global_load_lds into a 3-BUFFER rotation, vmcnt(8) counted waits:
// prefetch distance = 3 iterations (~1200cy >> L2 latency), zero VGPR cost.
// LDS = 136KB -> 1 block/CU -> backend targets 2 waves/SIMD -> 256-VGPR
// budget: starvation impossible by construction (r9-r11,r14 root cause).
// ---------------------------------------------------------------------------
__global__ __launch_bounds__(512) void k2_main(
    const int* __restrict__ adj, const ushort* __restrict__ hB,
    const float* __restrict__ s_src, const float* __restrict__ s_dst,
    float* __restrict__ out)
{
  const int tid = threadIdx.x;
  const int wv  = tid >> 6;
  const int h   = wv >> 1;            // head
  const int js  = wv & 1;             // j-half
  const int l   = tid & 63;
  const int L   = blockIdx.x;
  const int xcd = L & 7;
  const int b   = xcd >> 1;
  const int iblk = (xcd & 1) * 32 + (L >> 3);   // 64 i-blocks of 32 rows
  const int i0   = iblk << 5;
  const int bh   = b * NH + h;
  const int r16  = l & 15;
  const int grp  = l >> 4;
  const int koff = grp << 3;

  __shared__ ushort   hbuf[NH][2][3][2048];   // 96KB: [head][js][buf] 4KB
  __shared__ float    sdl[NH * NN];           // 32KB
  __shared__ unsigned abits[32][65];          // 8.3KB

  // ---- stage adj -> bits (32 rows x 2048)
  {
    const int srow = tid >> 4, sseg = tid & 15;
    const int* sb = adj + ((size_t)(b * NN + i0 + srow)) * NN + sseg * 128;
    #pragma unroll
    for (int p = 0; p < 4; ++p) {
      const i32x4 a0 = *(const i32x4*)(sb + p * 32);
      const i32x4 a1 = *(const i32x4*)(sb + p * 32 + 4);
      const i32x4 a2 = *(const i32x4*)(sb + p * 32 + 8);
      const i32x4 a3 = *(const i32x4*)(sb + p * 32 + 12);
      const i32x4 a4 = *(const i32x4*)(sb + p * 32 + 16);
      const i32x4 a5 = *(const i32x4*)(sb + p * 32 + 20);
      const i32x4 a6 = *(const i32x4*)(sb + p * 32 + 24);
      const i32x4 a7 = *(const i32x4*)(sb + p * 32 + 28);
      abits[srow][sseg * 4 + p] = pack16(a0, a1, a2, a3) | (pack16(a4, a5, a6, a7) << 16);
    }
  }
  // ---- stage s_dst (all heads), instruction-contiguous (conflict-free)
  {
    const float* sp = s_dst + (size_t)b * NH * NN;
    #pragma unroll
    for (int k = 0; k < 4; ++k) {
      const int di = k * 2048 + tid * 4;
      *(f32x4*)&sdl[di] = *(const f32x4*)(sp + di);
    }
  }
  __syncthreads();

  const float ssl0 = s_src[bh * NN + i0 + r16];
  const float ssl1 = s_src[bh * NN + i0 + 16 + r16];
  const ushort* hbSrc = hB + (size_t)bh * 131072 + l * 8;
  const float* sdh = &sdl[h * NN];
  const short8 ones = ONES8;
  const int base = js * 32;

  f32x4 acc[8];   // [s*4+t]
  #pragma unroll
  for (int q = 0; q < 8; ++q) acc[q] = (f32x4){0.f, 0.f, 0.f, 0.f};
  f32x4 acd0 = (f32x4){0.f, 0.f, 0.f, 0.f};
  f32x4 acd1 = (f32x4){0.f, 0.f, 0.f, 0.f};

#define STAGE(BUF, JC)                                                     \
  {                                                                        \
    _Pragma("unroll")                                                      \
    for (int t = 0; t < 4; ++t)                                            \
      gload_lds16(hbSrc + (size_t)(JC) * 2048 + t * 512,                   \
                  &hbuf[h][js][(BUF)][t * 512]);                           \
  }

#define BODY(JCL, BUF, DO_STAGE)                                           \
  {                                                                        \
    const int jcg = base + (JCL);                                          \
    const short8 hb0 = *(const short8*)&hbuf[h][js][(BUF)][l * 8];         \
    const short8 hb1 = *(const short8*)&hbuf[h][js][(BUF)][512 + l * 8];   \
    const short8 hb2 = *(const short8*)&hbuf[h][js][(BUF)][1024 + l * 8];  \
    const short8 hb3 = *(const short8*)&hbuf[h][js][(BUF)][1536 + l * 8];  \
    const int jb = jcg * 32 + koff;                                        \
    const f32x4 sd0 = *(const f32x4*)(sdh + jb);                           \
    const f32x4 sd1 = *(const f32x4*)(sdh + jb + 4);                       \
    const unsigned msk0 = abits[r16][jcg] >> koff;                         \
    const unsigned msk1 = abits[r16 + 16][jcg] >> koff;                    \
    asm volatile("s_waitcnt lgkmcnt(0)" ::: "memory");                     \
    __builtin_amdgcn_sched_barrier(0);                                     \
    if (DO_STAGE) STAGE((BUF), jcg + 3);                                   \
    float pl0[8], pl1[8];                                                  \
    _Pragma("unroll")                                                      \
    for (int e = 0; e < 8; ++e) {                                          \
      const float sdv = (e < 4) ? sd0[e] : sd1[e - 4];                     \
      float x = ssl0 + sdv;                                                \
      x = fmaxf(x, 0.2f * x);                                              \
      const float p = __builtin_amdgcn_exp2f(x);                           \
      pl0[e] = ((msk0 >> e) & 1u) ? p : 0.f;                               \
      float y = ssl1 + sdv;                                                \
      y = fmaxf(y, 0.2f * y);                                              \
      const float q = __builtin_amdgcn_exp2f(y);                           \
      pl1[e] = ((msk1 >> e) & 1u) ? q : 0.f;                               \
    }                                                                      \
    u32x4 pa, pb;                                                          \
    _Pragma("unroll")                                                      \
    for (int e2 = 0; e2 < 4; ++e2) {                                       \
      pa[e2] = cvtpk(pl0[2 * e2], pl0[2 * e2 + 1]);                        \
      pb[e2] = cvtpk(pl1[2 * e2], pl1[2 * e2 + 1]);                        \
    }                                                                      \
    union { u32x4 u; short8 s; } ca, cb; ca.u = pa; cb.u = pb;             \
    const short8 pal0 = ca.s, pal1 = cb.s;                                 \
    acc[0] = __builtin_amdgcn_mfma_f32_16x16x32_bf16(pal0, hb0, acc[0], 0, 0, 0); \
    acc[1] = __builtin_amdgcn_mfma_f32_16x16x32_bf16(pal0, hb1, acc[1], 0, 0, 0); \
    acc[2] = __builtin_amdgcn_mfma_f32_16x16x32_bf16(pal0, hb2, acc[2], 0, 0, 0); \
    acc[3] = __builtin_amdgcn_mfma_f32_16x16x32_bf16(pal0, hb3, acc[3], 0, 0, 0); \
    acd0   = __builtin_amdgcn_mfma_f32_16x16x32_bf16(pal0, ones, acd0,    0, 0, 0); \
    acc[4] = __builtin_amdgcn_mfma_f32_16x16x32_bf16(pal1, hb0, acc[4], 0, 0, 0); \
    acc[5] = __builtin_amdgcn_mfma_f32_16x16x32_bf16(pal1, hb1, acc[5], 0, 0, 0); \
    acc[6] = __builtin_amdgcn_mfma_f32_16x16x32_bf16(pal1, hb2, acc[6], 0, 0, 0); \
    acc[7] = __builtin_amdgcn_mfma_f32_16x16x32_bf16(pal1, hb3, acc[7], 0, 0, 0); \
    acd1   = __builtin_amdgcn_mfma_f32_16x16x32_bf16(pal1, ones, acd1,    0, 0, 0); \
  }

  // prologue: 3 buffers in flight (12 loads)
  STAGE(0, base);
  STAGE(1, base + 1);
  STAGE(2, base + 2);

  int buf = 0;
  #pragma unroll 1
  for (int jcL = 0; jcL < 29; ++jcL) {
    asm volatile("s_waitcnt vmcnt(8)" ::: "memory");
    BODY(jcL, buf, 1);
    buf = (buf == 2) ? 0 : buf + 1;
  }
  // tail: drain 8 -> 4 -> 0
  asm volatile("s_waitcnt vmcnt(8)" ::: "memory");
  BODY(29, buf, 0);
  buf = (buf == 2) ? 0 : buf + 1;
  asm volatile("s_waitcnt vmcnt(4)" ::: "memory");
  BODY(30, buf, 0);
  buf = (buf == 2) ? 0 : buf + 1;
  asm volatile("s_waitcnt vmcnt(0)" ::: "memory");
  BODY(31, buf, 0);
#undef BODY
#undef STAGE

  // ---- cross-js reduction: reuse hbuf as scratch (all DMA drained)
  __syncthreads();
  f32x4* red = (f32x4*)&hbuf[0][0][0][0];   // [h][10][64] f32x4 = 40KB
  if (js) {
    #pragma unroll
    for (int q = 0; q < 8; ++q) red[(h * 10 + q) * 64 + l] = acc[q];
    red[(h * 10 + 8) * 64 + l] = acd0;
    red[(h * 10 + 9) * 64 + l] = acd1;
  }
  __syncthreads();

  if (!js) {
    #pragma unroll
    for (int q = 0; q < 8; ++q) acc[q] += red[(h * 10 + q) * 64 + l];
    acd0 += red[(h * 10 + 8) * 64 + l];
    acd1 += red[(h * 10 + 9) * 64 + l];

    float rl[2][4];
    #pragma unroll
    for (int r = 0; r < 4; ++r) { rl[0][r] = 1.0f / acd0[r]; rl[1][r] = 1.0f / acd1[r]; }
    #pragma unroll
    for (int s = 0; s < 2; ++s) {
      #pragma unroll
      for (int t = 0; t < 4; ++t) {
        const f32x4 a = acc[s * 4 + t];
        #pragma unroll
        for (int r = 0; r < 4; ++r) {
          const int i = i0 + s * 16 + grp * 4 + r;
          const size_t oidx = ((size_t)(b * NN + i) * COLS) + h * 64 + t * 16 + r16;
          out[oidx] = a[r] * rl[s][r];
        }
      }
    }
  }
}

// ---------------------------------------------------------------------------
extern "C" void kernel_launch(void* const* d_in, const int* in_sizes, int n_in,
                              void* d_out, int out_size, void* d_ws, size_t ws_size,
                              hipStream_t stream) {
  const float* nf  = (const float*)d_in[0];
  const int*   adj = (const int*)d_in[1];
  const float* W   = (const float*)d_in[2];
  const float* att = (const float*)d_in[3];

  ushort* hB    = (ushort*)d_ws;                                  // 4 MB
  float*  s_src = (float*)((char*)d_ws + (size_t)16 * 64 * NN * 2);
  float*  s_dst = s_src + 16 * NN;

  hipLaunchKernelGGL(k1_prep, dim3(1024), dim3(256), 0, stream,
                     nf, W, att, hB, s_src, s_dst);
  hipLaunchKernelGGL(k2_main, dim3(256), dim3(512), 0, stream,
                     adj, hB, s_src, s_dst, (float*)d_out);
}